// Round 8
// baseline (291.907 us; speedup 1.0000x reference)
//
#include <hip/hip_runtime.h>
#include <math.h>

#define B_N 4096
#define D_DIM 512
#define MARGIN 0.2f
#define PAIR_EPS 1e-8f
#define NEG_INF (-INFINITY)

typedef __attribute__((ext_vector_type(8))) short bf16x8;
typedef __attribute__((ext_vector_type(4))) float f32x4;

// ws layout (bytes):
//   0x000000 : float accum[2] (total, count)
//   0x001000 : float sq[4096]
//   0x010000 : ushort Xh[4096*512]   (4 MB)
//   0x410000 : ushort Xl[4096*512]   (4 MB)
//   0x810000 : float4 part[16*16][256] (1 MB)
constexpr size_t WS_SQ   = 0x1000;
constexpr size_t WS_XH   = 0x10000;
constexpr size_t WS_XL   = 0x410000;
constexpr size_t WS_PART = 0x810000;

__device__ __forceinline__ unsigned short f2bf(float f) {
  unsigned int u = __float_as_uint(f);
  unsigned int r = (u + 0x7fffu + ((u >> 16) & 1u)) >> 16;  // RNE
  return (unsigned short)r;
}
__device__ __forceinline__ float bf2f(unsigned short h) {
  return __uint_as_float(((unsigned int)h) << 16);
}

typedef __attribute__((address_space(1))) const void* gptr_t;
typedef __attribute__((address_space(3))) void* lptr_t;
__device__ __forceinline__ void gload_lds16(const void* g, void* l) {
  __builtin_amdgcn_global_load_lds((gptr_t)g, (lptr_t)l, 16, 0, 0);
}

// ---------------- prep: accum init + sq + bf16 hi/lo split (fused) ----------------
__global__ __launch_bounds__(256) void k_prep(const float* __restrict__ batch,
                                              float* __restrict__ accum,
                                              float* __restrict__ sq,
                                              unsigned short* __restrict__ xh,
                                              unsigned short* __restrict__ xl) {
  if (blockIdx.x == 0 && threadIdx.x == 0) { accum[0] = 0.f; accum[1] = 0.f; }
  int row  = blockIdx.x * 4 + (threadIdx.x >> 6);
  int lane = threadIdx.x & 63;
  const size_t base = (size_t)row * D_DIM;
  float s = 0.f;
#pragma unroll
  for (int e = 0; e < 2; ++e) {
    const int off = lane * 4 + e * 256;
    float4 v = *(const float4*)(batch + base + off);
    ushort4 h, l;
    h.x = f2bf(v.x); l.x = f2bf(v.x - bf2f(h.x));
    h.y = f2bf(v.y); l.y = f2bf(v.y - bf2f(h.y));
    h.z = f2bf(v.z); l.z = f2bf(v.z - bf2f(h.z));
    h.w = f2bf(v.w); l.w = f2bf(v.w - bf2f(h.w));
    *(ushort4*)(xh + base + off) = h;
    *(ushort4*)(xl + base + off) = l;
    s += v.x * v.x + v.y * v.y + v.z * v.z + v.w * v.w;
  }
#pragma unroll
  for (int off = 32; off; off >>= 1) s += __shfl_xor(s, off);
  if (lane == 0) sq[row] = s;
}

// ---------------- GEMM: 256x256 tile, 8-phase counted-vmcnt, T2 swizzle -----------
// Virtual K = 1536: k-tile t in [0,24), phase p = t>>3 selects (Ah,Bh)/(Ah,Bl)/(Al,Bh).
// Per K-tile: 4 phases. Phase q: ds_read af(mi=2q,2q+1) [+q0: all bfv] ; stage 2
// quarter-tiles of tile t+1 ; barrier ; lgkmcnt(0) ; 16 MFMA ; [vmcnt gate] ; barrier.
// Stage schedule (tile t+1): q0:B.q01  q1:B.q23  q2:A.q02  q3:A.q13.
// Gates: end of q1: vmcnt(4)  (A(t).q13 landed before this tile's q2 reads);
//        end of q3: vmcnt(2)  (B(t+1) all + A(t+1).q02 landed before next p0 reads).
__global__ __launch_bounds__(512, 2) void k_gemm(
    const unsigned short* __restrict__ Xh, const unsigned short* __restrict__ Xl,
    const float* __restrict__ gpos, const float* __restrict__ gneg,
    const int* __restrict__ labels, const float* __restrict__ sq,
    float4* __restrict__ part) {
  __shared__ unsigned short As[2][256 * 64];   // 32KB x2 (parity = k-tile & 1)
  __shared__ unsigned short Bs[2][256 * 64];   // 32KB x2
  __shared__ float s_sqi[256], s_sqj[256];
  __shared__ int   s_lbi[256], s_lbj[256];

  const int jb = blockIdx.x, ib = blockIdx.y;
  const int i0 = ib * 256, j0 = jb * 256;
  const int tid = threadIdx.x;
  const int w = tid >> 6, lane = tid & 63;
  const int wm = w & 1, wn = w >> 1;          // 2 (M) x 4 (N) wave grid
  const int lr = lane & 15;                    // fragment row-lane
  const int lk = (lane >> 4) * 8;              // fragment k-offset (elems)

  if (tid < 256)      { s_sqi[tid] = sq[i0 + tid];       s_lbi[tid] = labels[i0 + tid]; }
  else                { int t = tid - 256; s_sqj[t] = sq[j0 + t]; s_lbj[t] = labels[j0 + t]; }

  f32x4 acc[8][4] = {};

  // staging lane geometry (verified R5, absmax 0): LDS dest linear, global source
  // column pre-swizzled so ds_read byte^((row&7)<<4) returns linear data (rule #21).
  const int srow = lane >> 3;                                  // 0..7
  const int scol = (((lane & 7) ^ (lane >> 3)) << 3);          // elems, swizzled

  // stage one 64-row quarter (1 gload_lds per thread; 64 rows x 128B)
#define STG_A(src, kk, np, qq)                                                    \
  gload_lds16((src) + (((size_t)(i0 + (qq) * 64 + w * 8 + srow) << 9) + (kk) + scol), \
              &As[np][(qq) * 4096 + w * 512])
#define STG_B(src, kk, np, qq)                                                    \
  gload_lds16((src) + (((size_t)(j0 + (qq) * 64 + w * 8 + srow) << 9) + (kk) + scol), \
              &Bs[np][(qq) * 4096 + w * 512])

  // ---- prologue: stage tile 0 (hi/hi, kk=0), A.q13 issued LAST (gate allows 2 fly)
  STG_B(Xh, 0, 0, 0); STG_B(Xh, 0, 0, 1); STG_B(Xh, 0, 0, 2); STG_B(Xh, 0, 0, 3);
  STG_A(Xh, 0, 0, 0); STG_A(Xh, 0, 0, 2);
  STG_A(Xh, 0, 0, 1); STG_A(Xh, 0, 0, 3);
  asm volatile("s_waitcnt vmcnt(2)" ::: "memory");
  __builtin_amdgcn_s_barrier();

#pragma unroll 1
  for (int t = 0; t < 24; ++t) {
    const int c = t & 1;
    const char* Ab = (const char*)&As[c][0];
    const char* Bb = (const char*)&Bs[c][0];
    // next-tile staging sources (virtual-K hi/lo select)
    const int n  = t + 1;
    const int np = n & 1;
    const int pn = n >> 3;
    const unsigned short* nA = (pn < 2) ? Xh : Xl;
    const unsigned short* nB = (pn == 1) ? Xl : Xh;
    const int nkk = (n & 7) * 64;

    bf16x8 bfv[4][2];
#pragma unroll
    for (int q = 0; q < 4; ++q) {
      // ---- ds reads for this phase (current tile)
      bf16x8 af[2][2];
#pragma unroll
      for (int ml = 0; ml < 2; ++ml) {
        const int row = wm * 128 + (2 * q + ml) * 16 + lr;
#pragma unroll
        for (int kx = 0; kx < 2; ++kx) {
          const int byt = ((row << 7) + ((kx * 32 + lk) << 1)) ^ ((lane & 7) << 4);
          af[ml][kx] = *(const bf16x8*)(Ab + byt);
        }
      }
      if (q == 0) {
#pragma unroll
        for (int ni = 0; ni < 4; ++ni) {
          const int row = wn * 64 + ni * 16 + lr;
#pragma unroll
          for (int kx = 0; kx < 2; ++kx) {
            const int byt = ((row << 7) + ((kx * 32 + lk) << 1)) ^ ((lane & 7) << 4);
            bfv[ni][kx] = *(const bf16x8*)(Bb + byt);
          }
        }
      }
      // ---- stage 2 quarter-tiles of tile t+1
      if (n < 24) {
        if (q == 0)      { STG_B(nB, nkk, np, 0); STG_B(nB, nkk, np, 1); }
        else if (q == 1) { STG_B(nB, nkk, np, 2); STG_B(nB, nkk, np, 3); }
        else if (q == 2) { STG_A(nA, nkk, np, 0); STG_A(nA, nkk, np, 2); }
        else             { STG_A(nA, nkk, np, 1); STG_A(nA, nkk, np, 3); }
      }
      __builtin_amdgcn_s_barrier();
      asm volatile("s_waitcnt lgkmcnt(0)" ::: "memory");
      __builtin_amdgcn_sched_barrier(0);
      __builtin_amdgcn_s_setprio(1);
#pragma unroll
      for (int kx = 0; kx < 2; ++kx)
#pragma unroll
        for (int ml = 0; ml < 2; ++ml)
#pragma unroll
          for (int ni = 0; ni < 4; ++ni)
            acc[2 * q + ml][ni] = __builtin_amdgcn_mfma_f32_16x16x32_bf16(
                af[ml][kx], bfv[ni][kx], acc[2 * q + ml][ni], 0, 0, 0);
      __builtin_amdgcn_s_setprio(0);
      // ---- counted gates (before the closing barrier; never 0 in steady state)
      if (q == 1) {
        if (t < 23) asm volatile("s_waitcnt vmcnt(4)" ::: "memory");
        else        asm volatile("s_waitcnt vmcnt(0)" ::: "memory");  // epilogue drain
      }
      if (q == 3) asm volatile("s_waitcnt vmcnt(2)" ::: "memory");
      __builtin_amdgcn_s_barrier();
    }
  }
#undef STG_A
#undef STG_B

  // ---- fused epilogue: d2 -> log_q -> +gumbel -> per-row argmax over this j-tile ----
  float4* red = (float4*)&As[0][0];   // alias (main loop done); 256 rows x 4 wn = 16KB
#pragma unroll
  for (int mi = 0; mi < 8; ++mi) {
#pragma unroll
    for (int r = 0; r < 4; ++r) {
      const int lrow = wm * 128 + mi * 16 + ((lane >> 4) << 2) + r;
      const int gi = i0 + lrow;
      const int li = s_lbi[lrow];
      const float sqi = s_sqi[lrow];
      float nv = NEG_INF; int nix = 0;
      float pv = NEG_INF; int pix = 0;
#pragma unroll
      for (int ni = 0; ni < 4; ++ni) {
        const int cj = wn * 64 + ni * 16 + lr;
        const int gj = j0 + cj;
        const float g = acc[mi][ni][r];
        float d2 = sqi + s_sqj[cj] - 2.f * g;
        float e2 = fmaxf(d2, 0.25f);   // dist clamps (1e-4, 0.5) => dist^2 = max(d2,0.25)
        float lq = -255.f * __logf(e2) - 254.5f * __logf(1.f - 0.25f * e2);
        const bool same = (li == s_lbj[cj]);
        float cn = same ? NEG_INF : lq + gneg[(size_t)gi * B_N + gj];
        if (cn > nv) { nv = cn; nix = gj; }
        float cp = NEG_INF;
        if (same & (gi != gj)) cp = gpos[(size_t)gi * B_N + gj];
        if (cp > pv) { pv = cp; pix = gj; }
      }
#pragma unroll
      for (int off = 1; off < 16; off <<= 1) {
        float onv = __shfl_xor(nv, off); int onix = __shfl_xor(nix, off);
        if (onv > nv || (onv == nv && onix < nix)) { nv = onv; nix = onix; }
        float opv = __shfl_xor(pv, off); int opix = __shfl_xor(pix, off);
        if (opv > pv || (opv == pv && opix < pix)) { pv = opv; pix = opix; }
      }
      if (lr == 0) red[lrow * 4 + wn] = make_float4(nv, __int_as_float(nix), pv, __int_as_float(pix));
    }
  }
  __syncthreads();
  if (tid < 256) {
    float nv = NEG_INF, pv = NEG_INF; int nix = 0, pix = 0;
#pragma unroll
    for (int q = 0; q < 4; ++q) {       // ascending wn = ascending j: first-index ties
      float4 e = red[tid * 4 + q];
      int eni = __float_as_int(e.y), epi = __float_as_int(e.w);
      if (e.x > nv || (e.x == nv && eni < nix)) { nv = e.x; nix = eni; }
      if (e.z > pv || (e.z == pv && epi < pix)) { pv = e.z; pix = epi; }
    }
    part[((size_t)(ib * 16 + jb)) * 256 + tid] =
        make_float4(nv, __int_as_float(nix), pv, __int_as_float(pix));
  }
}

// ---------------- final argmax across 16 j-tiles + triplet loss ----------------
__global__ __launch_bounds__(512) void k_reduce(const float* __restrict__ batch,
                                                const float* __restrict__ beta,
                                                const int* __restrict__ labels,
                                                const float4* __restrict__ part,
                                                float* __restrict__ accum) {
  __shared__ float2 s_bsum[8];
  const int wave = threadIdx.x >> 6, lane = threadIdx.x & 63;
  const int row = blockIdx.x * 8 + wave;
  float nv = NEG_INF, pv = NEG_INF;
  int nix = 0x7fffffff, pix = 0x7fffffff;
  if (lane < 16) {
    float4 p = part[((size_t)(row >> 8) * 16 + lane) * 256 + (row & 255)];
    nv = p.x; nix = __float_as_int(p.y);
    pv = p.z; pix = __float_as_int(p.w);
  }
#pragma unroll
  for (int off = 8; off; off >>= 1) {   // lanes 0..15 reduce among themselves
    float onv = __shfl_xor(nv, off); int onix = __shfl_xor(nix, off);
    if (onv > nv || (onv == nv && onix < nix)) { nv = onv; nix = onix; }
    float opv = __shfl_xor(pv, off); int opix = __shfl_xor(pix, off);
    if (opv > pv || (opv == pv && opix < pix)) { pv = opv; pix = opix; }
  }
  nix = __shfl(nix, 0); pix = __shfl(pix, 0);

  const float* xi = batch + (size_t)row * D_DIM;
  const float* xp = batch + (size_t)pix * D_DIM;
  const float* xn = batch + (size_t)nix * D_DIM;
  float sap = 0.f, san = 0.f;
#pragma unroll
  for (int e = 0; e < 2; ++e) {
    float4 a = ((const float4*)xi)[lane * 2 + e];
    float4 p = ((const float4*)xp)[lane * 2 + e];
    float4 n = ((const float4*)xn)[lane * 2 + e];
    float dx = a.x - p.x, dy = a.y - p.y, dz = a.z - p.z, dw = a.w - p.w;
    sap += dx * dx + dy * dy + dz * dz + dw * dw;
    dx = a.x - n.x; dy = a.y - n.y; dz = a.z - n.z; dw = a.w - n.w;
    san += dx * dx + dy * dy + dz * dz + dw * dw;
  }
#pragma unroll
  for (int off = 32; off; off >>= 1) {
    sap += __shfl_xor(sap, off);
    san += __shfl_xor(san, off);
  }
  if (lane == 0) {
    float d_ap = sqrtf(sap + PAIR_EPS);
    float d_an = sqrtf(san + PAIR_EPS);
    float b = beta[labels[row]];
    float pl = fmaxf(d_ap - b + MARGIN, 0.f);
    float nl = fmaxf(b - d_an + MARGIN, 0.f);
    float cnt = (pl > 0.f ? 1.f : 0.f) + (nl > 0.f ? 1.f : 0.f);
    s_bsum[wave] = make_float2(pl + nl, cnt);
  }
  __syncthreads();
  if (threadIdx.x == 0) {
    float tot = 0.f, cnt = 0.f;
#pragma unroll
    for (int q = 0; q < 8; ++q) { tot += s_bsum[q].x; cnt += s_bsum[q].y; }
    atomicAdd(&accum[0], tot);
    atomicAdd(&accum[1], cnt);
  }
}

__global__ void k_final(const float* __restrict__ accum, float* __restrict__ out) {
  float tot = accum[0], cnt = accum[1];
  out[0] = (cnt == 0.f) ? tot : tot / cnt;
}

extern "C" void kernel_launch(void* const* d_in, const int* in_sizes, int n_in,
                              void* d_out, int out_size, void* d_ws, size_t ws_size,
                              hipStream_t stream) {
  const float* batch  = (const float*)d_in[0];
  const float* beta   = (const float*)d_in[1];
  const float* gpos   = (const float*)d_in[2];
  const float* gneg   = (const float*)d_in[3];
  const int*   labels = (const int*)d_in[4];
  float* out = (float*)d_out;

  float*          accum = (float*)d_ws;
  float*          sq    = (float*)((char*)d_ws + WS_SQ);
  unsigned short* xh    = (unsigned short*)((char*)d_ws + WS_XH);
  unsigned short* xl    = (unsigned short*)((char*)d_ws + WS_XL);
  float4*         part  = (float4*)((char*)d_ws + WS_PART);

  k_prep<<<B_N / 4, 256, 0, stream>>>(batch, accum, sq, xh, xl);
  dim3 g(16, 16);
  k_gemm<<<g, 512, 0, stream>>>(xh, xl, gpos, gneg, labels, sq, part);
  k_reduce<<<B_N / 8, 512, 0, stream>>>(batch, beta, labels, part, accum);
  k_final<<<1, 1, 0, stream>>>(accum, out);
}